// Round 1
// baseline (525.959 us; speedup 1.0000x reference)
//
#include <hip/hip_runtime.h>
#include <math.h>

// Problem dims
#define NB 64
#define NT 1280
#define NP 1024
#define NF 256
#define ND 256

// ---------------- theta = W @ W^T (NT GEMM, 256x256x256) ----------------
__global__ __launch_bounds__(256) void theta_kernel(const float* __restrict__ W,
                                                    float* __restrict__ theta) {
    __shared__ float As[64][68];   // W rows [ib..], cols k   (natural)
    __shared__ float BsT[64][65];  // W rows [jb..] transposed: BsT[k][j]
    int tid = threadIdx.x;
    int ib = blockIdx.x * 64, jb = blockIdx.y * 64;
    int ty = tid >> 4, tx4 = (tid & 15) * 4;
    float acc[4][4] = {};
    for (int kb = 0; kb < 256; kb += 64) {
        #pragma unroll
        for (int i = 0; i < 4; ++i) {
            int e = tid * 4 + i * 1024;
            int r = e >> 6, c = e & 63;
            *(float4*)&As[r][c] = *(const float4*)(W + (size_t)(ib + r) * 256 + kb + c);
            float4 bv = *(const float4*)(W + (size_t)(jb + r) * 256 + kb + c);
            BsT[c + 0][r] = bv.x; BsT[c + 1][r] = bv.y;
            BsT[c + 2][r] = bv.z; BsT[c + 3][r] = bv.w;
        }
        __syncthreads();
        #pragma unroll
        for (int k = 0; k < 64; ++k) {
            float a[4], b[4];
            #pragma unroll
            for (int i = 0; i < 4; ++i) a[i] = As[ty * 4 + i][k];
            #pragma unroll
            for (int j = 0; j < 4; ++j) b[j] = BsT[k][tx4 + j];
            #pragma unroll
            for (int i = 0; i < 4; ++i)
                #pragma unroll
                for (int j = 0; j < 4; ++j) acc[i][j] += a[i] * b[j];
        }
        __syncthreads();
    }
    #pragma unroll
    for (int i = 0; i < 4; ++i) {
        float4 o = make_float4(acc[i][0], acc[i][1], acc[i][2], acc[i][3]);
        *(float4*)(theta + (size_t)(ib + ty * 4 + i) * 256 + jb + tx4) = o;
    }
}

// ---------------- mask[f][p] = (rowsoftmax(A[PAST+f, :NP], 0->-inf) >= 0.004) ----------------
__global__ __launch_bounds__(256) void mask_kernel(const float* __restrict__ A,
                                                   float* __restrict__ maskf) {
    int f = blockIdx.x;
    int tid = threadIdx.x;
    const float* row = A + (size_t)(NP + f) * NT;  // row PAST+f, cols 0..NP
    float4 v = *(const float4*)(row + tid * 4);
    float vals[4] = {v.x, v.y, v.z, v.w};
    float m = -1e30f;
    #pragma unroll
    for (int i = 0; i < 4; ++i)
        if (vals[i] != 0.f) m = fmaxf(m, vals[i]);
    __shared__ float red[256];
    red[tid] = m;
    __syncthreads();
    for (int s = 128; s > 0; s >>= 1) {
        if (tid < s) red[tid] = fmaxf(red[tid], red[tid + s]);
        __syncthreads();
    }
    m = red[0];
    __syncthreads();
    float e[4];
    float sloc = 0.f;
    #pragma unroll
    for (int i = 0; i < 4; ++i) {
        e[i] = (vals[i] != 0.f) ? expf(vals[i] - m) : 0.f;
        sloc += e[i];
    }
    red[tid] = sloc;
    __syncthreads();
    for (int s = 128; s > 0; s >>= 1) {
        if (tid < s) red[tid] += red[tid + s];
        __syncthreads();
    }
    float inv = 1.f / red[0];
    float4 o;
    o.x = (e[0] * inv >= 0.004f) ? 1.f : 0.f;
    o.y = (e[1] * inv >= 0.004f) ? 1.f : 0.f;
    o.z = (e[2] * inv >= 0.004f) ? 1.f : 0.f;
    o.w = (e[3] * inv >= 0.004f) ? 1.f : 0.f;
    *(float4*)(maskf + (size_t)f * NP + tid * 4) = o;
}

// ---------------- tx = X(81920x256) @ theta(256x256)  (NN GEMM) ----------------
__global__ __launch_bounds__(256) void txgemm_kernel(const float* __restrict__ X,
                                                     const float* __restrict__ Th,
                                                     float* __restrict__ TX) {
    __shared__ float As[64][68];  // X tile  [row][k]
    __shared__ float Bs[64][68];  // Th tile [k][col]
    int tid = threadIdx.x;
    int rb = blockIdx.x * 64, cb = blockIdx.y * 64;
    int ty = tid >> 4, tx4 = (tid & 15) * 4;
    float acc[4][4] = {};
    for (int kb = 0; kb < 256; kb += 64) {
        #pragma unroll
        for (int i = 0; i < 4; ++i) {
            int e = tid * 4 + i * 1024;
            int r = e >> 6, c = e & 63;
            *(float4*)&As[r][c] = *(const float4*)(X + (size_t)(rb + r) * 256 + kb + c);
            *(float4*)&Bs[r][c] = *(const float4*)(Th + (size_t)(kb + r) * 256 + cb + c);
        }
        __syncthreads();
        #pragma unroll
        for (int k = 0; k < 64; ++k) {
            float a[4];
            #pragma unroll
            for (int i = 0; i < 4; ++i) a[i] = As[ty * 4 + i][k];
            float4 bv = *(const float4*)&Bs[k][tx4];
            #pragma unroll
            for (int i = 0; i < 4; ++i) {
                acc[i][0] += a[i] * bv.x;
                acc[i][1] += a[i] * bv.y;
                acc[i][2] += a[i] * bv.z;
                acc[i][3] += a[i] * bv.w;
            }
        }
        __syncthreads();
    }
    #pragma unroll
    for (int i = 0; i < 4; ++i) {
        float4 o = make_float4(acc[i][0], acc[i][1], acc[i][2], acc[i][3]);
        *(float4*)(TX + (size_t)(rb + ty * 4 + i) * 256 + cb + tx4) = o;
    }
}

// ---------------- q[row] = dot(X[row], TX[row]) , one wave per row ----------------
__global__ __launch_bounds__(256) void q_kernel(const float* __restrict__ X,
                                                const float* __restrict__ TX,
                                                float* __restrict__ q) {
    int row = blockIdx.x * 4 + (threadIdx.x >> 6);
    int lane = threadIdx.x & 63;
    float4 a = *(const float4*)(X + (size_t)row * 256 + lane * 4);
    float4 b = *(const float4*)(TX + (size_t)row * 256 + lane * 4);
    float d = a.x * b.x + a.y * b.y + a.z * b.z + a.w * b.w;
    #pragma unroll
    for (int off = 32; off > 0; off >>= 1) d += __shfl_down(d, off, 64);
    if (lane == 0) q[row] = d;
}

// ---------------- L[b,f,p] = c*(2*S - qf - qp) masked, S = Xf . TxP^T (NT GEMM) ----------------
__global__ __launch_bounds__(256) void logits_kernel(const float* __restrict__ x,
                                                     const float* __restrict__ tx,
                                                     const float* __restrict__ q,
                                                     const float* __restrict__ maskf,
                                                     const float* __restrict__ sm,
                                                     float* __restrict__ Lbuf) {
    __shared__ float As[64][68];   // Xf tile [f][d]
    __shared__ float BsT[64][65];  // TxP tile transposed: BsT[d][p]
    int tid = threadIdx.x;
    int b = blockIdx.z;
    int fb = blockIdx.y * 64, pb = blockIdx.x * 64;
    int ty = tid >> 4, tx4 = (tid & 15) * 4;
    const float* Xf = x + (size_t)b * NT * ND + (size_t)NP * ND;
    const float* TxP = tx + (size_t)b * NT * ND;
    float acc[4][4] = {};
    for (int kb = 0; kb < 256; kb += 64) {
        #pragma unroll
        for (int i = 0; i < 4; ++i) {
            int e = tid * 4 + i * 1024;
            int r = e >> 6, c = e & 63;
            *(float4*)&As[r][c] = *(const float4*)(Xf + (size_t)(fb + r) * 256 + kb + c);
            float4 bv = *(const float4*)(TxP + (size_t)(pb + r) * 256 + kb + c);
            BsT[c + 0][r] = bv.x; BsT[c + 1][r] = bv.y;
            BsT[c + 2][r] = bv.z; BsT[c + 3][r] = bv.w;
        }
        __syncthreads();
        #pragma unroll
        for (int k = 0; k < 64; ++k) {
            float a[4], bb[4];
            #pragma unroll
            for (int i = 0; i < 4; ++i) a[i] = As[ty * 4 + i][k];
            #pragma unroll
            for (int j = 0; j < 4; ++j) bb[j] = BsT[k][tx4 + j];
            #pragma unroll
            for (int i = 0; i < 4; ++i)
                #pragma unroll
                for (int j = 0; j < 4; ++j) acc[i][j] += a[i] * bb[j];
        }
        __syncthreads();
    }
    float sg = 1.f / (1.f + expf(-sm[0]));
    float cc = 0.5f / (sg * 0.01f);
    #pragma unroll
    for (int i = 0; i < 4; ++i) {
        int f = fb + ty * 4 + i;
        float qf = q[b * NT + NP + f];
        float4 mv = *(const float4*)(maskf + (size_t)f * NP + pb + tx4);
        float mm[4] = {mv.x, mv.y, mv.z, mv.w};
        float vals[4];
        #pragma unroll
        for (int j = 0; j < 4; ++j) {
            int p = pb + tx4 + j;
            float qp = q[b * NT + p];
            float v = cc * (2.f * acc[i][j] - qf - qp);
            vals[j] = (mm[j] != 0.f) ? v : -1e30f;
        }
        float4 o = make_float4(vals[0], vals[1], vals[2], vals[3]);
        *(float4*)(Lbuf + (size_t)b * NF * NP + (size_t)f * NP + pb + tx4) = o;
    }
}

// ---------------- column (over f) max and 1/sum(exp) per (b,p) ----------------
__global__ __launch_bounds__(256) void colreduce_kernel(const float* __restrict__ Lbuf,
                                                        float* __restrict__ colM,
                                                        float* __restrict__ colR) {
    int b = blockIdx.y;
    int p = blockIdx.x * 256 + threadIdx.x;
    const float* Lb = Lbuf + (size_t)b * NF * NP + p;
    float m = -1e30f;
    #pragma unroll 8
    for (int f = 0; f < NF; ++f) m = fmaxf(m, Lb[(size_t)f * NP]);
    float s = 0.f;
    #pragma unroll 8
    for (int f = 0; f < NF; ++f) s += __expf(Lb[(size_t)f * NP] - m);
    float r;
    if (m <= -1e29f) { r = 0.f; m = 0.f; }  // fully-masked column -> zero weights
    else r = 1.f / s;
    colM[b * NP + p] = m;
    colR[b * NP + p] = r;
}

// ---------------- out[b] = softmax_w(256x1024) @ y[b](1024x256) ----------------
__global__ __launch_bounds__(256) void out_kernel(const float* __restrict__ Lbuf,
                                                  const float* __restrict__ colM,
                                                  const float* __restrict__ colR,
                                                  const float* __restrict__ y,
                                                  float* __restrict__ out) {
    __shared__ float As[64][68];  // w tile [f][p]
    __shared__ float Bs[64][68];  // y tile [p][d]
    int tid = threadIdx.x;
    int b = blockIdx.z;
    int fb = blockIdx.y * 64, db = blockIdx.x * 64;
    int ty = tid >> 4, tx4 = (tid & 15) * 4;
    const float* Lb = Lbuf + (size_t)b * NF * NP;
    const float* yb = y + (size_t)b * NP * ND;
    const float* Mb = colM + b * NP;
    const float* Rb = colR + b * NP;
    float acc[4][4] = {};
    for (int kb = 0; kb < NP; kb += 64) {
        #pragma unroll
        for (int i = 0; i < 4; ++i) {
            int e = tid * 4 + i * 1024;
            int r = e >> 6, c = e & 63;
            float4 lv = *(const float4*)(Lb + (size_t)(fb + r) * NP + kb + c);
            float4 mv = *(const float4*)(Mb + kb + c);
            float4 rv = *(const float4*)(Rb + kb + c);
            float4 w;
            w.x = __expf(lv.x - mv.x) * rv.x;
            w.y = __expf(lv.y - mv.y) * rv.y;
            w.z = __expf(lv.z - mv.z) * rv.z;
            w.w = __expf(lv.w - mv.w) * rv.w;
            *(float4*)&As[r][c] = w;
            *(float4*)&Bs[r][c] = *(const float4*)(yb + (size_t)(kb + r) * 256 + db + c);
        }
        __syncthreads();
        #pragma unroll
        for (int k = 0; k < 64; ++k) {
            float a[4];
            #pragma unroll
            for (int i = 0; i < 4; ++i) a[i] = As[ty * 4 + i][k];
            float4 bv = *(const float4*)&Bs[k][tx4];
            #pragma unroll
            for (int i = 0; i < 4; ++i) {
                acc[i][0] += a[i] * bv.x;
                acc[i][1] += a[i] * bv.y;
                acc[i][2] += a[i] * bv.z;
                acc[i][3] += a[i] * bv.w;
            }
        }
        __syncthreads();
    }
    #pragma unroll
    for (int i = 0; i < 4; ++i) {
        float4 o = make_float4(acc[i][0], acc[i][1], acc[i][2], acc[i][3]);
        *(float4*)(out + (size_t)b * NF * ND + (size_t)(fb + ty * 4 + i) * ND + db + tx4) = o;
    }
}

extern "C" void kernel_launch(void* const* d_in, const int* in_sizes, int n_in,
                              void* d_out, int out_size, void* d_ws, size_t ws_size,
                              hipStream_t stream) {
    const float* x = (const float*)d_in[0];
    const float* y = (const float*)d_in[1];
    const float* A = (const float*)d_in[2];
    const float* W = (const float*)d_in[3];
    const float* sm = (const float*)d_in[4];
    float* out = (float*)d_out;

    float* ws = (float*)d_ws;
    float* theta = ws;                                 // 65536
    float* maskf = theta + 256 * 256;                  // 262144
    float* q = maskf + 256 * 1024;                     // 81920
    float* colM = q + 64 * 1280;                       // 65536
    float* colR = colM + 64 * 1024;                    // 65536
    float* tx = colR + 64 * 1024;                      // 20971520
    float* Lbuf = tx + (size_t)64 * 1280 * 256;        // 16777216
    // total 38,289,408 floats = ~146 MiB

    theta_kernel<<<dim3(4, 4), 256, 0, stream>>>(W, theta);
    mask_kernel<<<dim3(256), 256, 0, stream>>>(A, maskf);
    txgemm_kernel<<<dim3(1280, 4), 256, 0, stream>>>(x, theta, tx);
    q_kernel<<<dim3(81920 / 4), 256, 0, stream>>>(x, tx, q);
    logits_kernel<<<dim3(16, 4, 64), 256, 0, stream>>>(x, tx, q, maskf, sm, Lbuf);
    colreduce_kernel<<<dim3(4, 64), 256, 0, stream>>>(Lbuf, colM, colR);
    out_kernel<<<dim3(4, 4, 64), 256, 0, stream>>>(Lbuf, colM, colR, y, out);
}

// Round 2
// 427.380 us; speedup vs baseline: 1.2307x; 1.2307x over previous
//
#include <hip/hip_runtime.h>
#include <math.h>

// Problem dims
#define NB 64
#define NT 1280
#define NP 1024
#define NF 256
#define ND 256

// ---------------- theta = W @ W^T (256x256x256) ---- unchanged ----
__global__ __launch_bounds__(256) void theta_kernel(const float* __restrict__ W,
                                                    float* __restrict__ theta) {
    __shared__ float As[64][68];
    __shared__ float BsT[64][65];
    int tid = threadIdx.x;
    int ib = blockIdx.x * 64, jb = blockIdx.y * 64;
    int ty = tid >> 4, tx4 = (tid & 15) * 4;
    float acc[4][4] = {};
    for (int kb = 0; kb < 256; kb += 64) {
        #pragma unroll
        for (int i = 0; i < 4; ++i) {
            int e = tid * 4 + i * 1024;
            int r = e >> 6, c = e & 63;
            *(float4*)&As[r][c] = *(const float4*)(W + (size_t)(ib + r) * 256 + kb + c);
            float4 bv = *(const float4*)(W + (size_t)(jb + r) * 256 + kb + c);
            BsT[c + 0][r] = bv.x; BsT[c + 1][r] = bv.y;
            BsT[c + 2][r] = bv.z; BsT[c + 3][r] = bv.w;
        }
        __syncthreads();
        #pragma unroll
        for (int k = 0; k < 64; ++k) {
            float a[4], b[4];
            #pragma unroll
            for (int i = 0; i < 4; ++i) a[i] = As[ty * 4 + i][k];
            #pragma unroll
            for (int j = 0; j < 4; ++j) b[j] = BsT[k][tx4 + j];
            #pragma unroll
            for (int i = 0; i < 4; ++i)
                #pragma unroll
                for (int j = 0; j < 4; ++j) acc[i][j] += a[i] * b[j];
        }
        __syncthreads();
    }
    #pragma unroll
    for (int i = 0; i < 4; ++i) {
        float4 o = make_float4(acc[i][0], acc[i][1], acc[i][2], acc[i][3]);
        *(float4*)(theta + (size_t)(ib + ty * 4 + i) * 256 + jb + tx4) = o;
    }
}

// ---------------- mask[f][p] ---- unchanged ----
__global__ __launch_bounds__(256) void mask_kernel(const float* __restrict__ A,
                                                   float* __restrict__ maskf) {
    int f = blockIdx.x;
    int tid = threadIdx.x;
    const float* row = A + (size_t)(NP + f) * NT;
    float4 v = *(const float4*)(row + tid * 4);
    float vals[4] = {v.x, v.y, v.z, v.w};
    float m = -1e30f;
    #pragma unroll
    for (int i = 0; i < 4; ++i)
        if (vals[i] != 0.f) m = fmaxf(m, vals[i]);
    __shared__ float red[256];
    red[tid] = m;
    __syncthreads();
    for (int s = 128; s > 0; s >>= 1) {
        if (tid < s) red[tid] = fmaxf(red[tid], red[tid + s]);
        __syncthreads();
    }
    m = red[0];
    __syncthreads();
    float e[4];
    float sloc = 0.f;
    #pragma unroll
    for (int i = 0; i < 4; ++i) {
        e[i] = (vals[i] != 0.f) ? expf(vals[i] - m) : 0.f;
        sloc += e[i];
    }
    red[tid] = sloc;
    __syncthreads();
    for (int s = 128; s > 0; s >>= 1) {
        if (tid < s) red[tid] += red[tid + s];
        __syncthreads();
    }
    float inv = 1.f / red[0];
    float4 o;
    o.x = (e[0] * inv >= 0.004f) ? 1.f : 0.f;
    o.y = (e[1] * inv >= 0.004f) ? 1.f : 0.f;
    o.z = (e[2] * inv >= 0.004f) ? 1.f : 0.f;
    o.w = (e[3] * inv >= 0.004f) ? 1.f : 0.f;
    *(float4*)(maskf + (size_t)f * NP + tid * 4) = o;
}

// ------- generic 128x128 fp32 GEMM: C = A(MxK, k-contig) @ B(KxN, n-contig) -------
// grid: (N/128, M/128, batch), 256 threads, 8x8 acc (2x2 grid of 4x4 fragments)
__global__ __launch_bounds__(256) void gemm128_kernel(const float* __restrict__ Ag, size_t sA,
                                                      const float* __restrict__ Bg, size_t sB,
                                                      float* __restrict__ Cg, size_t sC,
                                                      int lda, int ldb, int ldc, int K) {
    __shared__ float As[32][132];   // As[k][r], pad 132 -> 4-way max on staging writes
    __shared__ float Bs[32][128];   // Bs[k][c]
    int tid = threadIdx.x;
    int bz = blockIdx.z;
    const float* A = Ag + sA * bz;
    const float* B = Bg + sB * bz;
    float* C = Cg + sC * bz;
    int cb = blockIdx.x * 128, rb = blockIdx.y * 128;
    int tx = tid & 15, ty = tid >> 4;
    int sr = tid >> 3, sc = (tid & 7) * 4;
    int br = tid >> 5, bc = (tid & 31) * 4;
    float acc[8][8] = {};
    for (int kb = 0; kb < K; kb += 32) {
        #pragma unroll
        for (int pass = 0; pass < 4; ++pass) {
            int r = sr + pass * 32;
            float4 g = *(const float4*)(A + (size_t)(rb + r) * lda + kb + sc);
            As[sc + 0][r] = g.x; As[sc + 1][r] = g.y;
            As[sc + 2][r] = g.z; As[sc + 3][r] = g.w;
        }
        #pragma unroll
        for (int pass = 0; pass < 4; ++pass) {
            int r = br + pass * 8;
            *(float4*)&Bs[r][bc] = *(const float4*)(B + (size_t)(kb + r) * ldb + cb + bc);
        }
        __syncthreads();
        #pragma unroll
        for (int k = 0; k < 32; ++k) {
            float4 a0 = *(const float4*)&As[k][ty * 4];
            float4 a1 = *(const float4*)&As[k][64 + ty * 4];
            float4 b0 = *(const float4*)&Bs[k][tx * 4];
            float4 b1 = *(const float4*)&Bs[k][64 + tx * 4];
            float a[8] = {a0.x, a0.y, a0.z, a0.w, a1.x, a1.y, a1.z, a1.w};
            float b[8] = {b0.x, b0.y, b0.z, b0.w, b1.x, b1.y, b1.z, b1.w};
            #pragma unroll
            for (int i = 0; i < 8; ++i)
                #pragma unroll
                for (int j = 0; j < 8; ++j) acc[i][j] += a[i] * b[j];
        }
        __syncthreads();
    }
    #pragma unroll
    for (int i = 0; i < 8; ++i) {
        int row = rb + (i < 4 ? ty * 4 + i : 64 + ty * 4 + i - 4);
        float4 o0 = make_float4(acc[i][0], acc[i][1], acc[i][2], acc[i][3]);
        float4 o1 = make_float4(acc[i][4], acc[i][5], acc[i][6], acc[i][7]);
        *(float4*)(C + (size_t)row * ldc + cb + tx * 4) = o0;
        *(float4*)(C + (size_t)row * ldc + cb + 64 + tx * 4) = o1;
    }
}

// ---------------- q[row] = dot(X[row], TX[row]) ---- unchanged ----
__global__ __launch_bounds__(256) void q_kernel(const float* __restrict__ X,
                                                const float* __restrict__ TX,
                                                float* __restrict__ q) {
    int row = blockIdx.x * 4 + (threadIdx.x >> 6);
    int lane = threadIdx.x & 63;
    float4 a = *(const float4*)(X + (size_t)row * 256 + lane * 4);
    float4 b = *(const float4*)(TX + (size_t)row * 256 + lane * 4);
    float d = a.x * b.x + a.y * b.y + a.z * b.z + a.w * b.w;
    #pragma unroll
    for (int off = 32; off > 0; off >>= 1) d += __shfl_down(d, off, 64);
    if (lane == 0) q[row] = d;
}

// ------- fused logits + column(f) softmax -> normalized weights Wbuf[b][f][p] -------
// tile: f = 256 (all), p = 64. grid (16 p-tiles, 64 b), 256 threads.
__global__ __launch_bounds__(256) void logits_fused_kernel(const float* __restrict__ x,
                                                           const float* __restrict__ txg,
                                                           const float* __restrict__ q,
                                                           const float* __restrict__ maskf,
                                                           const float* __restrict__ sm,
                                                           float* __restrict__ Wbuf) {
    __shared__ float Af[32][260];   // [k][f]
    __shared__ float Bp[32][68];    // [k][p]
    __shared__ float red[16][68];
    __shared__ float colM_s[64], colR_s[64];
    __shared__ float qf_s[256], qp_s[64];
    int tid = threadIdx.x;
    int b = blockIdx.y;
    int pb = blockIdx.x * 64;
    int tx = tid & 15, ty = tid >> 4;
    const float* Xf = x + (size_t)b * NT * ND + (size_t)NP * ND;
    const float* Txb = txg + (size_t)b * NT * ND;
    qf_s[tid] = q[b * NT + NP + tid];
    if (tid < 64) qp_s[tid] = q[b * NT + pb + tid];
    int sr = tid >> 3, sc = (tid & 7) * 4;
    float acc[16][4] = {};
    for (int kb = 0; kb < 256; kb += 32) {
        #pragma unroll
        for (int pass = 0; pass < 8; ++pass) {
            int r = sr + pass * 32;
            float4 g = *(const float4*)(Xf + (size_t)r * 256 + kb + sc);
            Af[sc + 0][r] = g.x; Af[sc + 1][r] = g.y;
            Af[sc + 2][r] = g.z; Af[sc + 3][r] = g.w;
        }
        #pragma unroll
        for (int pass = 0; pass < 2; ++pass) {
            int r = sr + pass * 32;
            float4 g = *(const float4*)(Txb + (size_t)(pb + r) * 256 + kb + sc);
            Bp[sc + 0][r] = g.x; Bp[sc + 1][r] = g.y;
            Bp[sc + 2][r] = g.z; Bp[sc + 3][r] = g.w;
        }
        __syncthreads();
        #pragma unroll
        for (int k = 0; k < 32; ++k) {
            float4 bv = *(const float4*)&Bp[k][tx * 4];
            float bj[4] = {bv.x, bv.y, bv.z, bv.w};
            #pragma unroll
            for (int s = 0; s < 4; ++s) {
                float4 av = *(const float4*)&Af[k][s * 64 + ty * 4];
                float ai[4] = {av.x, av.y, av.z, av.w};
                #pragma unroll
                for (int i = 0; i < 4; ++i)
                    #pragma unroll
                    for (int j = 0; j < 4; ++j) acc[s * 4 + i][j] += ai[i] * bj[j];
            }
        }
        __syncthreads();
    }
    float sg = 1.f / (1.f + expf(-sm[0]));
    float cc = 0.5f / (sg * 0.01f);
    #pragma unroll
    for (int s = 0; s < 4; ++s)
        #pragma unroll
        for (int i = 0; i < 4; ++i) {
            int f = s * 64 + ty * 4 + i;
            float qf = qf_s[f];
            float4 mv = *(const float4*)(maskf + (size_t)f * NP + pb + tx * 4);
            float mm[4] = {mv.x, mv.y, mv.z, mv.w};
            #pragma unroll
            for (int j = 0; j < 4; ++j) {
                float qp = qp_s[tx * 4 + j];
                float v = cc * (2.f * acc[s * 4 + i][j] - qf - qp);
                acc[s * 4 + i][j] = (mm[j] != 0.f) ? v : -1e30f;
            }
        }
    // column max over f
    float lm[4] = {-1e30f, -1e30f, -1e30f, -1e30f};
    #pragma unroll
    for (int r = 0; r < 16; ++r)
        #pragma unroll
        for (int j = 0; j < 4; ++j) lm[j] = fmaxf(lm[j], acc[r][j]);
    *(float4*)&red[ty][tx * 4] = make_float4(lm[0], lm[1], lm[2], lm[3]);
    __syncthreads();
    if (tid < 64) {
        float m = -1e30f;
        #pragma unroll
        for (int t = 0; t < 16; ++t) m = fmaxf(m, red[t][tid]);
        colM_s[tid] = m;
    }
    __syncthreads();
    // column sum of exp
    float ls[4] = {0.f, 0.f, 0.f, 0.f};
    #pragma unroll
    for (int j = 0; j < 4; ++j) {
        float m = colM_s[tx * 4 + j];
        #pragma unroll
        for (int r = 0; r < 16; ++r) ls[j] += __expf(acc[r][j] - m);
    }
    __syncthreads();
    *(float4*)&red[ty][tx * 4] = make_float4(ls[0], ls[1], ls[2], ls[3]);
    __syncthreads();
    if (tid < 64) {
        float ssum = 0.f;
        #pragma unroll
        for (int t = 0; t < 16; ++t) ssum += red[t][tid];
        colR_s[tid] = (colM_s[tid] <= -1e29f) ? 0.f : 1.f / ssum;
    }
    __syncthreads();
    // normalized weights
    #pragma unroll
    for (int s = 0; s < 4; ++s)
        #pragma unroll
        for (int i = 0; i < 4; ++i) {
            int f = s * 64 + ty * 4 + i;
            float w[4];
            #pragma unroll
            for (int j = 0; j < 4; ++j) {
                float m = colM_s[tx * 4 + j];
                float r = colR_s[tx * 4 + j];
                w[j] = __expf(acc[s * 4 + i][j] - m) * r;
            }
            *(float4*)(Wbuf + (size_t)b * NF * NP + (size_t)f * NP + pb + tx * 4) =
                make_float4(w[0], w[1], w[2], w[3]);
        }
}

extern "C" void kernel_launch(void* const* d_in, const int* in_sizes, int n_in,
                              void* d_out, int out_size, void* d_ws, size_t ws_size,
                              hipStream_t stream) {
    const float* x = (const float*)d_in[0];
    const float* y = (const float*)d_in[1];
    const float* A = (const float*)d_in[2];
    const float* W = (const float*)d_in[3];
    const float* sm = (const float*)d_in[4];
    float* out = (float*)d_out;

    float* ws = (float*)d_ws;
    float* theta = ws;                                 // 65536
    float* maskf = theta + 256 * 256;                  // 262144
    float* q = maskf + 256 * 1024;                     // 81920
    float* tx = q + 64 * 1280;                         // 20971520
    float* Wbuf = tx + (size_t)64 * 1280 * 256;        // 16777216
    // total ~145.6 MiB

    theta_kernel<<<dim3(4, 4), 256, 0, stream>>>(W, theta);
    mask_kernel<<<dim3(256), 256, 0, stream>>>(A, maskf);
    // TX = x(81920x256) @ theta(256x256)
    gemm128_kernel<<<dim3(2, 640, 1), 256, 0, stream>>>(x, 0, theta, 0, tx, 0,
                                                        256, 256, 256, 256);
    q_kernel<<<dim3(81920 / 4), 256, 0, stream>>>(x, tx, q);
    logits_fused_kernel<<<dim3(16, 64), 256, 0, stream>>>(x, tx, q, maskf, sm, Wbuf);
    // out[b] = Wbuf[b](256x1024) @ y[b](1024x256)
    gemm128_kernel<<<dim3(2, 2, 64), 256, 0, stream>>>(Wbuf, (size_t)NF * NP,
                                                       y, (size_t)NP * ND,
                                                       out, (size_t)NF * ND,
                                                       NP, ND, ND, NP);
}